// Round 1
// baseline (134.854 us; speedup 1.0000x reference)
//
#include <hip/hip_runtime.h>
#include <hip/hip_bf16.h>
#include <cstddef>

#define BN_EPS 1e-5f

// ---------------------------------------------------------------------------
// Shapes: query (100,4,256)  value (4,256,64,64)  W1 (1024,256)  W2 (512,1024)
//         Wl (18,100)  Wd (100,18)
// Outputs: q (100,4,256) then y (4,256,64,64), concatenated flat in d_out.
// ---------------------------------------------------------------------------

// Kernel A: pooled[b*256+c] = mean over 64x64 plane
__global__ __launch_bounds__(256) void pool_kernel(const float* __restrict__ value,
                                                   float* __restrict__ pooled) {
    int bc = blockIdx.x;
    int t  = threadIdx.x;
    const float* vp = value + (size_t)bc * 4096;
    float s = 0.f;
    #pragma unroll
    for (int i = 0; i < 16; ++i) s += vp[i * 256 + t];
    // wave64 reduce
    #pragma unroll
    for (int off = 32; off > 0; off >>= 1) s += __shfl_down(s, off);
    __shared__ float ws4[4];
    if ((t & 63) == 0) ws4[t >> 6] = s;
    __syncthreads();
    if (t == 0) pooled[bc] = (ws4[0] + ws4[1] + ws4[2] + ws4[3]) * (1.0f / 4096.0f);
}

// Kernel B1: dp = relu(BN(pooled @ W1^T + b1))   -> (4,1024)
__global__ __launch_bounds__(256) void fc1_kernel(const float* __restrict__ pooled,
                                                  const float* __restrict__ W1,
                                                  const float* __restrict__ b1,
                                                  const float* __restrict__ gamma,
                                                  const float* __restrict__ beta,
                                                  const float* __restrict__ mean,
                                                  const float* __restrict__ var,
                                                  float* __restrict__ dp) {
    int gid = blockIdx.x * 256 + threadIdx.x;   // 0..4095
    int b = gid >> 10, j = gid & 1023;
    const float* pr = pooled + b * 256;
    const float* wr = W1 + (size_t)j * 256;
    float s = b1[j];
    #pragma unroll 4
    for (int c = 0; c < 256; ++c) s = fmaf(pr[c], wr[c], s);
    s = (s - mean[j]) * rsqrtf(var[j] + BN_EPS) * gamma[j] + beta[j];
    dp[gid] = fmaxf(s, 0.f);
}

// Kernel B2: dc = sigmoid(dp @ W2^T + b2) -> former_ch (4,256), weight_ch (4,256)
__global__ __launch_bounds__(256) void fc2_kernel(const float* __restrict__ dp,
                                                  const float* __restrict__ W2,
                                                  const float* __restrict__ b2,
                                                  float* __restrict__ fch,
                                                  float* __restrict__ wch) {
    int gid = blockIdx.x * 256 + threadIdx.x;   // 0..2047
    int b = gid >> 9, j = gid & 511;
    const float* dr = dp + b * 1024;
    const float* wr = W2 + (size_t)j * 1024;
    float s = b2[j];
    #pragma unroll 4
    for (int i = 0; i < 1024; ++i) s = fmaf(dr[i], wr[i], s);
    float sg = __builtin_amdgcn_rcpf(1.0f + __expf(-s));
    if (j < 256) fch[b * 256 + j]       = sg;
    else         wch[b * 256 + (j-256)] = sg;
}

// Kernel C: lin/former/wk + q output.  One thread per (b,c).  4 blocks x 256.
__global__ __launch_bounds__(256) void head_kernel(const float* __restrict__ query,
                                                   const float* __restrict__ Wl,
                                                   const float* __restrict__ bl,
                                                   const float* __restrict__ Wd,
                                                   const float* __restrict__ bd,
                                                   const float* __restrict__ fch,
                                                   const float* __restrict__ wch,
                                                   float* __restrict__ former,
                                                   float* __restrict__ wk,
                                                   float* __restrict__ q_out) {
    __shared__ float sWl[18 * 100];
    __shared__ float sWd[100 * 18];
    int t = threadIdx.x;
    for (int i = t; i < 1800; i += 256) { sWl[i] = Wl[i]; sWd[i] = Wd[i]; }
    __syncthreads();
    int bc = blockIdx.x * 256 + t;              // 0..1023
    float acc[18];
    #pragma unroll
    for (int k = 0; k < 18; ++k) acc[k] = bl[k];
    for (int q = 0; q < 100; ++q) {
        float qv = query[q * 1024 + bc];
        #pragma unroll
        for (int k = 0; k < 18; ++k) acc[k] = fmaf(qv, sWl[k * 100 + q], acc[k]);
    }
    float fc = fch[bc], wc = wch[bc];
    float cat[18];
    #pragma unroll
    for (int k = 0; k < 9; ++k) { cat[k] = acc[k] * fc; cat[9 + k] = acc[9 + k] * wc; }
    #pragma unroll
    for (int k = 0; k < 9; ++k) { former[bc * 9 + k] = cat[k]; wk[bc * 9 + k] = cat[9 + k]; }
    for (int qi = 0; qi < 100; ++qi) {
        float s = bd[qi];
        #pragma unroll
        for (int k = 0; k < 18; ++k) s = fmaf(cat[k], sWd[qi * 18 + k], s);
        q_out[qi * 1024 + bc] = s;
    }
}

// Kernel D: the two-stage 3x3 stencil.  One block per (b,c) plane.
// Dstack[k,y,x] = value[y-dy_k, x-dx_k] (zero-padded), k order: dy in {1,0,-1}
// outer, dx in {1,0,-1} inner.  With vpad[yy][xx] = value[yy-1][xx-1], the k-th
// neighbor of pixel (y,x) is vpad[y + ky][x + kx], k = ky*3+kx (ky=1-dy, kx=1-dx).
__global__ __launch_bounds__(256) void main_kernel(const float* __restrict__ value,
                                                   const float* __restrict__ former,
                                                   const float* __restrict__ wk,
                                                   float* __restrict__ y_out) {
    __shared__ float vpad[66 * 66];
    __shared__ float ppad[66 * 66];
    int bc = blockIdx.x;
    int t  = threadIdx.x;

    for (int i = t; i < 66 * 66; i += 256) { vpad[i] = 0.f; ppad[i] = 0.f; }
    __syncthreads();

    const float* vp = value + (size_t)bc * 4096;
    #pragma unroll
    for (int i = 0; i < 16; ++i) {
        int idx = i * 256 + t;
        int y = idx >> 6, x = idx & 63;
        vpad[(y + 1) * 66 + (x + 1)] = vp[idx];
    }
    float f[9], wkk[9];
    #pragma unroll
    for (int k = 0; k < 9; ++k) { f[k] = former[bc * 9 + k]; wkk[k] = wk[bc * 9 + k]; }
    __syncthreads();

    float yt[16], pc[16];
    #pragma unroll
    for (int i = 0; i < 16; ++i) {
        int idx = i * 256 + t;
        int y = idx >> 6, x = idx & 63;
        const float* base = &vpad[y * 66 + x];
        float s = 0.f;
        #pragma unroll
        for (int ky = 0; ky < 3; ++ky)
            #pragma unroll
            for (int kx = 0; kx < 3; ++kx)
                s = fmaf(f[ky * 3 + kx], base[ky * 66 + kx], s);
        float vc = base[66 + 1];
        float d  = vc - s;
        float df = __expf(-d * d);
        yt[i] = s;
        pc[i] = df * vc;
        ppad[(y + 1) * 66 + (x + 1)] = pc[i];
    }
    __syncthreads();

    #pragma unroll
    for (int i = 0; i < 16; ++i) {
        int idx = i * 256 + t;
        int y = idx >> 6, x = idx & 63;
        const float* vb = &vpad[y * 66 + x];
        const float* pb = &ppad[y * 66 + x];
        float prodc = pc[i];
        float yd = 0.f;
        #pragma unroll
        for (int ky = 0; ky < 3; ++ky)
            #pragma unroll
            for (int kx = 0; kx < 3; ++kx) {
                float vn = vb[ky * 66 + kx];
                float pn = pb[ky * 66 + kx];
                float dw = fabsf(pn - prodc);
                float sig = __builtin_amdgcn_rcpf(1.0f + __expf(-dw));
                yd = fmaf(sig * vn, wkk[ky * 3 + kx], yd);
            }
        y_out[(size_t)bc * 4096 + idx] = yt[i] - yd;
    }
}

extern "C" void kernel_launch(void* const* d_in, const int* in_sizes, int n_in,
                              void* d_out, int out_size, void* d_ws, size_t ws_size,
                              hipStream_t stream) {
    const float* query = (const float*)d_in[0];
    const float* value = (const float*)d_in[1];
    // d_in[2] hard_sigmoid_masks: unused by the reference
    const float* W1    = (const float*)d_in[3];
    const float* b1    = (const float*)d_in[4];
    const float* gamma = (const float*)d_in[5];
    const float* beta  = (const float*)d_in[6];
    const float* mean  = (const float*)d_in[7];
    const float* var   = (const float*)d_in[8];
    const float* W2    = (const float*)d_in[9];
    const float* b2    = (const float*)d_in[10];
    const float* Wl    = (const float*)d_in[11];
    const float* bl    = (const float*)d_in[12];
    const float* Wd    = (const float*)d_in[13];
    const float* bd    = (const float*)d_in[14];

    float* ws = (float*)d_ws;
    float* pooled = ws;            // 1024
    float* dp     = ws + 1024;     // 4096
    float* fch    = ws + 5120;     // 1024
    float* wch    = ws + 6144;     // 1024
    float* former = ws + 7168;     // 9216
    float* wkbuf  = ws + 16384;    // 9216

    float* q_out = (float*)d_out;            // 102400 floats
    float* y_out = (float*)d_out + 102400;   // 4194304 floats

    hipLaunchKernelGGL(pool_kernel, dim3(1024), dim3(256), 0, stream, value, pooled);
    hipLaunchKernelGGL(fc1_kernel,  dim3(16),   dim3(256), 0, stream,
                       pooled, W1, b1, gamma, beta, mean, var, dp);
    hipLaunchKernelGGL(fc2_kernel,  dim3(8),    dim3(256), 0, stream,
                       dp, W2, b2, fch, wch);
    hipLaunchKernelGGL(head_kernel, dim3(4),    dim3(256), 0, stream,
                       query, Wl, bl, Wd, bd, fch, wch, former, wkbuf, q_out);
    hipLaunchKernelGGL(main_kernel, dim3(1024), dim3(256), 0, stream,
                       value, former, wkbuf, y_out);
}

// Round 2
// 42.942 us; speedup vs baseline: 3.1404x; 3.1404x over previous
//
#include <hip/hip_runtime.h>
#include <hip/hip_bf16.h>
#include <cstddef>

#define BN_EPS 1e-5f

// Shapes: query (100,4,256)  value (4,256,64,64)  W1 (1024,256)  W2 (512,1024)
//         Wl (18,100)  Wd (100,18)
// Outputs: q (100,4,256) then y (4,256,64,64), concatenated flat in d_out.

// Kernel A: pooled[b*256+c] = mean over 64x64 plane
__global__ __launch_bounds__(256) void pool_kernel(const float* __restrict__ value,
                                                   float* __restrict__ pooled) {
    int bc = blockIdx.x;
    int t  = threadIdx.x;
    const float* vp = value + (size_t)bc * 4096;
    float s = 0.f;
    #pragma unroll
    for (int i = 0; i < 16; ++i) s += vp[i * 256 + t];
    #pragma unroll
    for (int off = 32; off > 0; off >>= 1) s += __shfl_down(s, off);
    __shared__ float ws4[4];
    if ((t & 63) == 0) ws4[t >> 6] = s;
    __syncthreads();
    if (t == 0) pooled[bc] = (ws4[0] + ws4[1] + ws4[2] + ws4[3]) * (1.0f / 4096.0f);
}

// Kernel B1: dp = relu(BN(pooled @ W1^T + b1)) -> (4,1024).  One wave per output.
__global__ __launch_bounds__(256) void fc1_kernel(const float* __restrict__ pooled,
                                                  const float* __restrict__ W1,
                                                  const float* __restrict__ b1,
                                                  const float* __restrict__ gamma,
                                                  const float* __restrict__ beta,
                                                  const float* __restrict__ mean,
                                                  const float* __restrict__ var,
                                                  float* __restrict__ dp) {
    int wid  = blockIdx.x * 4 + (threadIdx.x >> 6);   // 0..4095
    int lane = threadIdx.x & 63;
    int b = wid >> 10, j = wid & 1023;
    const float4* pr = (const float4*)(pooled + b * 256);        // 64 x float4
    const float4* wr = (const float4*)(W1 + (size_t)j * 256);
    float4 p = pr[lane], w = wr[lane];
    float s = p.x * w.x + p.y * w.y + p.z * w.z + p.w * w.w;
    #pragma unroll
    for (int off = 32; off > 0; off >>= 1) s += __shfl_down(s, off);
    if (lane == 0) {
        s += b1[j];
        s = (s - mean[j]) * rsqrtf(var[j] + BN_EPS) * gamma[j] + beta[j];
        dp[wid] = fmaxf(s, 0.f);
    }
}

// Kernel B2: dc = sigmoid(dp @ W2^T + b2).  One wave per output (2048 waves).
__global__ __launch_bounds__(256) void fc2_kernel(const float* __restrict__ dp,
                                                  const float* __restrict__ W2,
                                                  const float* __restrict__ b2,
                                                  float* __restrict__ fch,
                                                  float* __restrict__ wch) {
    int wid  = blockIdx.x * 4 + (threadIdx.x >> 6);   // 0..2047
    int lane = threadIdx.x & 63;
    int b = wid >> 9, j = wid & 511;
    const float4* dr = (const float4*)(dp + b * 1024);           // 256 x float4
    const float4* wr = (const float4*)(W2 + (size_t)j * 1024);
    float s = 0.f;
    #pragma unroll
    for (int i = 0; i < 4; ++i) {
        float4 a = dr[lane + 64 * i], w = wr[lane + 64 * i];
        s += a.x * w.x + a.y * w.y + a.z * w.z + a.w * w.w;
    }
    #pragma unroll
    for (int off = 32; off > 0; off >>= 1) s += __shfl_down(s, off);
    if (lane == 0) {
        s += b2[j];
        float sg = __builtin_amdgcn_rcpf(1.0f + __expf(-s));
        if (j < 256) fch[b * 256 + j]         = sg;
        else         wch[b * 256 + (j - 256)] = sg;
    }
}

// Kernel C: cat[bc][k] = (sum_q query[q,bc] * Wl[k,q] + bl[k]) * gate.
// One thread per (k,bc): 18432 threads, 72 blocks.  Lanes share k -> Wl broadcast,
// query reads coalesced.
__global__ __launch_bounds__(256) void head_cat_kernel(const float* __restrict__ query,
                                                       const float* __restrict__ Wl,
                                                       const float* __restrict__ bl,
                                                       const float* __restrict__ fch,
                                                       const float* __restrict__ wch,
                                                       float* __restrict__ former,
                                                       float* __restrict__ wkbuf,
                                                       float* __restrict__ catbuf) {
    __shared__ float sWl[18 * 100];
    int t = threadIdx.x;
    for (int i = t; i < 1800; i += 256) sWl[i] = Wl[i];
    __syncthreads();
    int g  = blockIdx.x * 256 + t;     // 0..18431
    int k  = g >> 10, bc = g & 1023;
    float s = bl[k];
    const float* wlr = &sWl[k * 100];
    #pragma unroll 4
    for (int q = 0; q < 100; ++q) s = fmaf(query[q * 1024 + bc], wlr[q], s);
    float gch = (k < 9) ? fch[bc] : wch[bc];
    float v = s * gch;
    catbuf[bc * 18 + k] = v;
    if (k < 9) former[bc * 9 + k]       = v;
    else       wkbuf [bc * 9 + (k - 9)] = v;
}

// Kernel D: two-stage 3x3 stencil (blocks 0..1023, one per (b,c) plane)
// + q projection (blocks 1024..1423, one thread per (qi,bc)).
__global__ __launch_bounds__(256) void main_kernel(const float* __restrict__ value,
                                                   const float* __restrict__ former,
                                                   const float* __restrict__ wk,
                                                   const float* __restrict__ catbuf,
                                                   const float* __restrict__ Wd,
                                                   const float* __restrict__ bd,
                                                   float* __restrict__ q_out,
                                                   float* __restrict__ y_out) {
    if (blockIdx.x >= 1024) {
        int g  = (blockIdx.x - 1024) * 256 + threadIdx.x;   // 0..102399
        int qi = g >> 10, bc = g & 1023;
        float s = bd[qi];
        const float* cr = catbuf + bc * 18;
        const float* wr = Wd + qi * 18;
        #pragma unroll
        for (int k = 0; k < 18; ++k) s = fmaf(cr[k], wr[k], s);
        q_out[g] = s;
        return;
    }

    __shared__ float vpad[66 * 66];
    __shared__ float ppad[66 * 66];
    int bc = blockIdx.x;
    int t  = threadIdx.x;

    for (int i = t; i < 66 * 66; i += 256) { vpad[i] = 0.f; ppad[i] = 0.f; }
    __syncthreads();

    const float* vp = value + (size_t)bc * 4096;
    #pragma unroll
    for (int i = 0; i < 16; ++i) {
        int idx = i * 256 + t;
        int y = idx >> 6, x = idx & 63;
        vpad[(y + 1) * 66 + (x + 1)] = vp[idx];
    }
    float f[9], wkk[9];
    #pragma unroll
    for (int k = 0; k < 9; ++k) { f[k] = former[bc * 9 + k]; wkk[k] = wk[bc * 9 + k]; }
    __syncthreads();

    float yt[16], pc[16];
    #pragma unroll
    for (int i = 0; i < 16; ++i) {
        int idx = i * 256 + t;
        int y = idx >> 6, x = idx & 63;
        const float* base = &vpad[y * 66 + x];
        float s = 0.f;
        #pragma unroll
        for (int ky = 0; ky < 3; ++ky)
            #pragma unroll
            for (int kx = 0; kx < 3; ++kx)
                s = fmaf(f[ky * 3 + kx], base[ky * 66 + kx], s);
        float vc = base[66 + 1];
        float d  = vc - s;
        float df = __expf(-d * d);
        yt[i] = s;
        pc[i] = df * vc;
        ppad[(y + 1) * 66 + (x + 1)] = pc[i];
    }
    __syncthreads();

    #pragma unroll
    for (int i = 0; i < 16; ++i) {
        int idx = i * 256 + t;
        int y = idx >> 6, x = idx & 63;
        const float* vb = &vpad[y * 66 + x];
        const float* pb = &ppad[y * 66 + x];
        float prodc = pc[i];
        float yd = 0.f;
        #pragma unroll
        for (int ky = 0; ky < 3; ++ky)
            #pragma unroll
            for (int kx = 0; kx < 3; ++kx) {
                float vn = vb[ky * 66 + kx];
                float pn = pb[ky * 66 + kx];
                float dw = fabsf(pn - prodc);
                float sig = __builtin_amdgcn_rcpf(1.0f + __expf(-dw));
                yd = fmaf(sig * vn, wkk[ky * 3 + kx], yd);
            }
        y_out[(size_t)bc * 4096 + idx] = yt[i] - yd;
    }
}

extern "C" void kernel_launch(void* const* d_in, const int* in_sizes, int n_in,
                              void* d_out, int out_size, void* d_ws, size_t ws_size,
                              hipStream_t stream) {
    const float* query = (const float*)d_in[0];
    const float* value = (const float*)d_in[1];
    // d_in[2] hard_sigmoid_masks: unused by the reference
    const float* W1    = (const float*)d_in[3];
    const float* b1    = (const float*)d_in[4];
    const float* gamma = (const float*)d_in[5];
    const float* beta  = (const float*)d_in[6];
    const float* mean  = (const float*)d_in[7];
    const float* var   = (const float*)d_in[8];
    const float* W2    = (const float*)d_in[9];
    const float* b2    = (const float*)d_in[10];
    const float* Wl    = (const float*)d_in[11];
    const float* bl    = (const float*)d_in[12];
    const float* Wd    = (const float*)d_in[13];
    const float* bd    = (const float*)d_in[14];

    float* ws = (float*)d_ws;
    float* pooled = ws;            // 1024
    float* dp     = ws + 1024;     // 4096
    float* fch    = ws + 5120;     // 1024
    float* wch    = ws + 6144;     // 1024
    float* former = ws + 7168;     // 9216
    float* wkbuf  = ws + 16384;    // 9216
    float* catbuf = ws + 25600;    // 18432

    float* q_out = (float*)d_out;            // 102400 floats
    float* y_out = (float*)d_out + 102400;   // 4194304 floats

    hipLaunchKernelGGL(pool_kernel,     dim3(1024), dim3(256), 0, stream, value, pooled);
    hipLaunchKernelGGL(fc1_kernel,      dim3(1024), dim3(256), 0, stream,
                       pooled, W1, b1, gamma, beta, mean, var, dp);
    hipLaunchKernelGGL(fc2_kernel,      dim3(512),  dim3(256), 0, stream,
                       dp, W2, b2, fch, wch);
    hipLaunchKernelGGL(head_cat_kernel, dim3(72),   dim3(256), 0, stream,
                       query, Wl, bl, fch, wch, former, wkbuf, catbuf);
    hipLaunchKernelGGL(main_kernel,     dim3(1424), dim3(256), 0, stream,
                       value, former, wkbuf, catbuf, Wd, bd, q_out, y_out);
}

// Round 4
// 38.146 us; speedup vs baseline: 3.5352x; 1.1257x over previous
//
#include <hip/hip_runtime.h>
#include <cstddef>

#define BN_EPS 1e-5f
#define VST 68   // LDS row stride (floats): 272B = 17*16B, bank advance 4/row

__device__ __forceinline__ float sigmoidf_(float x) {
    return __builtin_amdgcn_rcpf(1.0f + __expf(-x));
}

// K1: pool (blocks 0..1023) + lin = query.Wl + bl (blocks 1024..1095)
__global__ __launch_bounds__(256) void pool_lin_kernel(
    const float* __restrict__ value, const float* __restrict__ query,
    const float* __restrict__ Wl, const float* __restrict__ bl,
    float* __restrict__ pooled, float* __restrict__ linbuf) {
    int t = threadIdx.x;
    if (blockIdx.x >= 1024) {
        __shared__ float sWl[1800];
        for (int i = t; i < 1800; i += 256) sWl[i] = Wl[i];
        __syncthreads();
        int g = (blockIdx.x - 1024) * 256 + t;     // 0..18431
        int k = g >> 10, bc = g & 1023;
        float s = bl[k];
        const float* wlr = &sWl[k * 100];
        #pragma unroll 4
        for (int q = 0; q < 100; ++q) s = fmaf(query[q * 1024 + bc], wlr[q], s);
        linbuf[bc * 18 + k] = s;
        return;
    }
    int bc = blockIdx.x;
    const float4* vp = (const float4*)(value + (size_t)bc * 4096);
    float s = 0.f;
    #pragma unroll
    for (int i = 0; i < 4; ++i) {
        float4 v = vp[t + 256 * i];
        s += v.x + v.y + v.z + v.w;
    }
    #pragma unroll
    for (int off = 32; off > 0; off >>= 1) s += __shfl_down(s, off);
    __shared__ float ws4[4];
    if ((t & 63) == 0) ws4[t >> 6] = s;
    __syncthreads();
    if (t == 0) pooled[bc] = (ws4[0] + ws4[1] + ws4[2] + ws4[3]) * (1.0f / 4096.0f);
}

// K2: dp = relu(BN(pooled @ W1^T + b1)) -> (4,1024).  One wave per output.
__global__ __launch_bounds__(256) void fc1_kernel(
    const float* __restrict__ pooled, const float* __restrict__ W1,
    const float* __restrict__ b1, const float* __restrict__ gamma,
    const float* __restrict__ beta, const float* __restrict__ mean,
    const float* __restrict__ var, float* __restrict__ dp) {
    int wid  = blockIdx.x * 4 + (threadIdx.x >> 6);   // 0..4095
    int lane = threadIdx.x & 63;
    int b = wid >> 10, j = wid & 1023;
    const float4* pr = (const float4*)(pooled + b * 256);
    const float4* wr = (const float4*)(W1 + (size_t)j * 256);
    float4 p = pr[lane], w = wr[lane];
    float s = p.x * w.x + p.y * w.y + p.z * w.z + p.w * w.w;
    #pragma unroll
    for (int off = 32; off > 0; off >>= 1) s += __shfl_down(s, off);
    if (lane == 0) {
        s += b1[j];
        s = (s - mean[j]) * rsqrtf(var[j] + BN_EPS) * gamma[j] + beta[j];
        dp[wid] = fmaxf(s, 0.f);
    }
}

// K3: gates (fc2) + gate-multiply.  One wave per bc (1024 waves, 256 blocks).
__global__ __launch_bounds__(256) void gate_kernel(
    const float* __restrict__ dp, const float* __restrict__ W2,
    const float* __restrict__ b2, const float* __restrict__ linbuf,
    float* __restrict__ catbuf) {
    int t = threadIdx.x, w = t >> 6, lane = t & 63;
    int bc = blockIdx.x * 4 + w, b = bc >> 8, c = bc & 255;
    const float4* dpr = (const float4*)(dp + b * 1024);
    const float4* wA  = (const float4*)(W2 + (size_t)c * 1024);
    const float4* wB  = (const float4*)(W2 + (size_t)(c + 256) * 1024);
    float sA = 0.f, sB = 0.f;
    #pragma unroll
    for (int j = 0; j < 4; ++j) {
        float4 d = dpr[lane + 64 * j];
        float4 a = wA[lane + 64 * j];
        float4 e = wB[lane + 64 * j];
        sA += d.x * a.x + d.y * a.y + d.z * a.z + d.w * a.w;
        sB += d.x * e.x + d.y * e.y + d.z * e.z + d.w * e.w;
    }
    #pragma unroll
    for (int off = 32; off > 0; off >>= 1) {
        sA += __shfl_xor(sA, off);
        sB += __shfl_xor(sB, off);
    }
    float gA = sigmoidf_(sA + b2[c]);
    float gB = sigmoidf_(sB + b2[c + 256]);
    if (lane < 18) {
        float v = linbuf[bc * 18 + lane] * (lane < 9 ? gA : gB);
        catbuf[bc * 18 + lane] = v;
    }
}

// K4: two-stage 3x3 stencil, strip-per-thread (blocks 0..1023)
//     + q projection (blocks 1024..1423).
// vpad[row][col]: plane value[y][x] at row=y+1, col=x+3; halo cells zero.
// Neighbor k=(ky,kx) of pixel (y,x) lives at row y+ky, col 2+x+kx.
__global__ __launch_bounds__(256, 4) void main_kernel(
    const float* __restrict__ value, const float* __restrict__ catbuf,
    const float* __restrict__ Wd, const float* __restrict__ bd,
    float* __restrict__ q_out, float* __restrict__ y_out) {
    if (blockIdx.x >= 1024) {
        int g = (blockIdx.x - 1024) * 256 + threadIdx.x;   // 0..102399
        int qi = g >> 10, bc = g & 1023;
        float s = bd[qi];
        const float* cr = catbuf + bc * 18;
        const float* wr = Wd + qi * 18;
        #pragma unroll
        for (int k = 0; k < 18; ++k) s = fmaf(cr[k], wr[k], s);
        q_out[g] = s;
        return;
    }
    __shared__ __align__(16) float vpad[66 * VST];
    __shared__ __align__(16) float ppad[66 * VST];
    int bc = blockIdx.x, t = threadIdx.x;

    // zero the 260 halo cells that reads touch (rows 0,65 cols 2..67;
    // cols 2,67 rows 1..64).  NOTE: 260 > blockDim, must stride.
    for (int i = t; i < 260; i += 256) {
        int row, col;
        if (i < 132) { row = (i & 1) ? 65 : 0; col = 2 + (i >> 1); }
        else { int u = i - 132; row = 1 + (u & 63); col = (u & 64) ? 67 : 2; }
        vpad[row * VST + col] = 0.f;
        ppad[row * VST + col] = 0.f;
    }
    // load value plane (coalesced scalar -> conflict-free LDS writes)
    const float* vp = value + (size_t)bc * 4096;
    #pragma unroll
    for (int i = 0; i < 16; ++i) {
        int idx = (i << 8) + t;
        vpad[((idx >> 6) + 1) * VST + 3 + (idx & 63)] = vp[idx];
    }
    float f[9], wkk[9];
    const float* cb = catbuf + bc * 18;
    #pragma unroll
    for (int k = 0; k < 9; ++k) { f[k] = cb[k]; wkk[k] = cb[9 + k]; }
    __syncthreads();

    int r  = t >> 2;            // row 0..63
    int xo = (t & 3) << 4;      // 0,16,32,48

    float yt[16], vc[16];
    #pragma unroll
    for (int i = 0; i < 16; ++i) yt[i] = 0.f;

    // stage 1: y_temp = 3x3 conv(value, f)
    #pragma unroll
    for (int dy = 0; dy < 3; ++dy) {
        const float4* rp = (const float4*)&vpad[(r + dy) * VST + xo];
        float rw[20];
        *(float4*)&rw[0]  = rp[0]; *(float4*)&rw[4]  = rp[1];
        *(float4*)&rw[8]  = rp[2]; *(float4*)&rw[12] = rp[3];
        *(float4*)&rw[16] = rp[4];
        #pragma unroll
        for (int i = 0; i < 16; ++i) {
            yt[i] = fmaf(f[dy * 3 + 0], rw[2 + i], yt[i]);
            yt[i] = fmaf(f[dy * 3 + 1], rw[3 + i], yt[i]);
            yt[i] = fmaf(f[dy * 3 + 2], rw[4 + i], yt[i]);
        }
        if (dy == 1) {
            #pragma unroll
            for (int i = 0; i < 16; ++i) vc[i] = rw[3 + i];
        }
    }
    // prod = exp(-(v - y_temp)^2) * v
    float pc[16];
    #pragma unroll
    for (int i = 0; i < 16; ++i) {
        float d = vc[i] - yt[i];
        pc[i] = __expf(-d * d) * vc[i];
        ppad[(r + 1) * VST + 3 + xo + i] = pc[i];
    }
    __syncthreads();

    // stage 2: y = y_temp - sum_k sig(|prod_k - prod_c|) * value_k * wk_k
    #pragma unroll
    for (int dy = 0; dy < 3; ++dy) {
        const float4* rp = (const float4*)&vpad[(r + dy) * VST + xo];
        const float4* pp = (const float4*)&ppad[(r + dy) * VST + xo];
        float vr[20], prw[20];
        *(float4*)&vr[0]   = rp[0]; *(float4*)&vr[4]   = rp[1];
        *(float4*)&vr[8]   = rp[2]; *(float4*)&vr[12]  = rp[3];
        *(float4*)&vr[16]  = rp[4];
        *(float4*)&prw[0]  = pp[0]; *(float4*)&prw[4]  = pp[1];
        *(float4*)&prw[8]  = pp[2]; *(float4*)&prw[12] = pp[3];
        *(float4*)&prw[16] = pp[4];
        #pragma unroll
        for (int i = 0; i < 16; ++i) {
            float prodc = pc[i];
            #pragma unroll
            for (int kx = 0; kx < 3; ++kx) {
                float vn = vr[2 + i + kx];
                float pn = prw[2 + i + kx];
                float dw = fabsf(pn - prodc);
                float sg = sigmoidf_(dw);
                yt[i] = fmaf(-sg * vn, wkk[dy * 3 + kx], yt[i]);
            }
        }
    }
    // store strip (4 x dwordx4, coalesced)
    size_t base = (size_t)bc * 4096 + r * 64 + xo;
    #pragma unroll
    for (int i = 0; i < 4; ++i) {
        float4 o = make_float4(yt[4*i], yt[4*i+1], yt[4*i+2], yt[4*i+3]);
        *(float4*)&y_out[base + 4 * i] = o;
    }
}

extern "C" void kernel_launch(void* const* d_in, const int* in_sizes, int n_in,
                              void* d_out, int out_size, void* d_ws, size_t ws_size,
                              hipStream_t stream) {
    const float* query = (const float*)d_in[0];
    const float* value = (const float*)d_in[1];
    // d_in[2] hard_sigmoid_masks: unused by the reference
    const float* W1    = (const float*)d_in[3];
    const float* b1    = (const float*)d_in[4];
    const float* gamma = (const float*)d_in[5];
    const float* beta  = (const float*)d_in[6];
    const float* mean  = (const float*)d_in[7];
    const float* var   = (const float*)d_in[8];
    const float* W2    = (const float*)d_in[9];
    const float* b2    = (const float*)d_in[10];
    const float* Wl    = (const float*)d_in[11];
    const float* bl    = (const float*)d_in[12];
    const float* Wd    = (const float*)d_in[13];
    const float* bd    = (const float*)d_in[14];

    float* ws = (float*)d_ws;
    float* pooled = ws;            // 1024
    float* dp     = ws + 1024;     // 4096
    float* linbuf = ws + 5120;     // 18432
    float* catbuf = ws + 23552;    // 18432

    float* q_out = (float*)d_out;            // 102400 floats
    float* y_out = (float*)d_out + 102400;   // 4194304 floats

    hipLaunchKernelGGL(pool_lin_kernel, dim3(1096), dim3(256), 0, stream,
                       value, query, Wl, bl, pooled, linbuf);
    hipLaunchKernelGGL(fc1_kernel,      dim3(1024), dim3(256), 0, stream,
                       pooled, W1, b1, gamma, beta, mean, var, dp);
    hipLaunchKernelGGL(gate_kernel,     dim3(256),  dim3(256), 0, stream,
                       dp, W2, b2, linbuf, catbuf);
    hipLaunchKernelGGL(main_kernel,     dim3(1424), dim3(256), 0, stream,
                       value, catbuf, Wd, bd, q_out, y_out);
}

// Round 6
// 37.810 us; speedup vs baseline: 3.5666x; 1.0089x over previous
//
#include <hip/hip_runtime.h>
#include <cstddef>

#define BN_EPS 1e-5f
#define VST 68   // LDS row stride (floats): 272B = 17*16B -> 16B-aligned rows

__device__ __forceinline__ float sigmoidf_(float x) {
    return __builtin_amdgcn_rcpf(1.0f + __expf(-x));
}

// K1: pool (blocks 0..1023) + lin = query.Wl + bl (blocks 1024..1095)
__global__ __launch_bounds__(256) void pool_lin_kernel(
    const float* __restrict__ value, const float* __restrict__ query,
    const float* __restrict__ Wl, const float* __restrict__ bl,
    float* __restrict__ pooled, float* __restrict__ linbuf) {
    int t = threadIdx.x;
    if (blockIdx.x >= 1024) {
        __shared__ float sWl[1800];
        for (int i = t; i < 1800; i += 256) sWl[i] = Wl[i];
        __syncthreads();
        int g = (blockIdx.x - 1024) * 256 + t;     // 0..18431
        int k = g >> 10, bc = g & 1023;
        float s = bl[k];
        const float* wlr = &sWl[k * 100];
        #pragma unroll 4
        for (int q = 0; q < 100; ++q) s = fmaf(query[q * 1024 + bc], wlr[q], s);
        linbuf[bc * 18 + k] = s;
        return;
    }
    int bc = blockIdx.x;
    const float4* vp = (const float4*)(value + (size_t)bc * 4096);
    float s = 0.f;
    #pragma unroll
    for (int i = 0; i < 4; ++i) {
        float4 v = vp[t + 256 * i];
        s += v.x + v.y + v.z + v.w;
    }
    #pragma unroll
    for (int off = 32; off > 0; off >>= 1) s += __shfl_down(s, off);
    __shared__ float ws4[4];
    if ((t & 63) == 0) ws4[t >> 6] = s;
    __syncthreads();
    if (t == 0) pooled[bc] = (ws4[0] + ws4[1] + ws4[2] + ws4[3]) * (1.0f / 4096.0f);
}

// K2: dp = relu(BN(pooled @ W1^T + b1)) -> (4,1024).  One wave per output.
__global__ __launch_bounds__(256) void fc1_kernel(
    const float* __restrict__ pooled, const float* __restrict__ W1,
    const float* __restrict__ b1, const float* __restrict__ gamma,
    const float* __restrict__ beta, const float* __restrict__ mean,
    const float* __restrict__ var, float* __restrict__ dp) {
    int wid  = blockIdx.x * 4 + (threadIdx.x >> 6);   // 0..4095
    int lane = threadIdx.x & 63;
    int b = wid >> 10, j = wid & 1023;
    const float4* pr = (const float4*)(pooled + b * 256);
    const float4* wr = (const float4*)(W1 + (size_t)j * 256);
    float4 p = pr[lane], w = wr[lane];
    float s = p.x * w.x + p.y * w.y + p.z * w.z + p.w * w.w;
    #pragma unroll
    for (int off = 32; off > 0; off >>= 1) s += __shfl_down(s, off);
    if (lane == 0) {
        s += b1[j];
        s = (s - mean[j]) * rsqrtf(var[j] + BN_EPS) * gamma[j] + beta[j];
        dp[wid] = fmaxf(s, 0.f);
    }
}

// K3: fused fc2-gates + two-stage 3x3 stencil + q projection.
// One block per (b,c) plane (1024 blocks, 256 threads).
// vpad[row][col]: plane value[y][x] at row=y+1, col=x+3; halo cells zero.
// Neighbor k=(ky,kx) of pixel (y,x) lives at row y+ky, col 2+x+kx.
__global__ __launch_bounds__(256, 4) void stencil_kernel(
    const float* __restrict__ value, const float* __restrict__ dp,
    const float* __restrict__ W2, const float* __restrict__ b2,
    const float* __restrict__ linbuf, const float* __restrict__ Wd,
    const float* __restrict__ bd,
    float* __restrict__ q_out, float* __restrict__ y_out) {

    __shared__ __align__(16) float vpad[66 * VST];
    __shared__ __align__(16) float ppad[66 * VST];
    __shared__ float scat[18];
    __shared__ float gAB[2];

    const int t  = threadIdx.x;
    const int bc = blockIdx.x;            // 0..1023
    const int b  = bc >> 8, c = bc & 255;
    const int w  = t >> 6, lane = t & 63;

    // fc2 gate dots (waves 0,1) -- issue global loads early
    float sgate = 0.f;
    if (w < 2) {
        const float4* dpr  = (const float4*)(dp + b * 1024);
        const float4* wrow = (const float4*)(W2 + (size_t)(c + w * 256) * 1024);
        #pragma unroll
        for (int j = 0; j < 4; ++j) {
            float4 d = dpr[lane + 64 * j], ww = wrow[lane + 64 * j];
            sgate += d.x * ww.x + d.y * ww.y + d.z * ww.z + d.w * ww.w;
        }
    }

    // halo zero: 260 cells (rows 0,65 cols 2..67; cols 2,67 rows 1..64)
    for (int i = t; i < 260; i += 256) {
        int row, col;
        if (i < 132) { row = (i & 1) ? 65 : 0; col = 2 + (i >> 1); }
        else { int u = i - 132; row = 1 + (u & 63); col = (u & 64) ? 67 : 2; }
        vpad[row * VST + col] = 0.f;
        ppad[row * VST + col] = 0.f;
    }
    // load value plane (coalesced -> conflict-free LDS writes)
    const float* vp = value + (size_t)bc * 4096;
    #pragma unroll
    for (int i = 0; i < 16; ++i) {
        int idx = (i << 8) + t;
        vpad[((idx >> 6) + 1) * VST + 3 + (idx & 63)] = vp[idx];
    }

    // finish gates
    if (w < 2) {
        #pragma unroll
        for (int off = 32; off > 0; off >>= 1) sgate += __shfl_xor(sgate, off);
        if (lane == 0) gAB[w] = sigmoidf_(sgate + b2[c + w * 256]);
    }
    float lv = (t < 18) ? linbuf[bc * 18 + t] : 0.f;
    __syncthreads();
    if (t < 18) scat[t] = lv * (t < 9 ? gAB[0] : gAB[1]);
    __syncthreads();

    float f[9], wkk[9];
    #pragma unroll
    for (int k = 0; k < 9; ++k) { f[k] = scat[k]; wkk[k] = scat[9 + k]; }

    // ---- stage 1: y_temp = 3x3 conv(value, f), strip per thread ----
    const int r  = t >> 2;                // row 0..63
    const int xo = (t & 3) << 4;          // 0,16,32,48

    float yt[16], vc[16];
    #pragma unroll
    for (int i = 0; i < 16; ++i) yt[i] = 0.f;

    #pragma unroll
    for (int dy = 0; dy < 3; ++dy) {
        const float4* rp = (const float4*)&vpad[(r + dy) * VST + xo];
        float rw[20];
        *(float4*)&rw[0]  = rp[0]; *(float4*)&rw[4]  = rp[1];
        *(float4*)&rw[8]  = rp[2]; *(float4*)&rw[12] = rp[3];
        *(float4*)&rw[16] = rp[4];
        #pragma unroll
        for (int i = 0; i < 16; ++i) {
            yt[i] = fmaf(f[dy * 3 + 0], rw[2 + i], yt[i]);
            yt[i] = fmaf(f[dy * 3 + 1], rw[3 + i], yt[i]);
            yt[i] = fmaf(f[dy * 3 + 2], rw[4 + i], yt[i]);
        }
        if (dy == 1) {
            #pragma unroll
            for (int i = 0; i < 16; ++i) vc[i] = rw[3 + i];
        }
    }
    float pc[16];
    #pragma unroll
    for (int i = 0; i < 16; ++i) {
        float d = vc[i] - yt[i];
        pc[i] = __expf(-d * d) * vc[i];
        ppad[(r + 1) * VST + 3 + xo + i] = pc[i];
    }
    __syncthreads();

    // ---- stage 2: y = y_temp - sum_k sig(|prod_k - prod_c|) * value_k * wk_k
    #pragma unroll
    for (int dy = 0; dy < 3; ++dy) {
        const float4* rp = (const float4*)&vpad[(r + dy) * VST + xo];
        const float4* pp = (const float4*)&ppad[(r + dy) * VST + xo];
        float vr[20], prw[20];
        *(float4*)&vr[0]   = rp[0]; *(float4*)&vr[4]   = rp[1];
        *(float4*)&vr[8]   = rp[2]; *(float4*)&vr[12]  = rp[3];
        *(float4*)&vr[16]  = rp[4];
        *(float4*)&prw[0]  = pp[0]; *(float4*)&prw[4]  = pp[1];
        *(float4*)&prw[8]  = pp[2]; *(float4*)&prw[12] = pp[3];
        *(float4*)&prw[16] = pp[4];
        #pragma unroll
        for (int i = 0; i < 16; ++i) {
            float prodc = pc[i];
            #pragma unroll
            for (int kx = 0; kx < 3; ++kx) {
                float vn = vr[2 + i + kx];
                float pn = prw[2 + i + kx];
                float dw = fabsf(pn - prodc);
                float sg = sigmoidf_(dw);
                yt[i] = fmaf(-sg * vn, wkk[dy * 3 + kx], yt[i]);
            }
        }
    }
    size_t base = (size_t)bc * 4096 + r * 64 + xo;
    #pragma unroll
    for (int i = 0; i < 4; ++i) {
        float4 o = make_float4(yt[4*i], yt[4*i+1], yt[4*i+2], yt[4*i+3]);
        *(float4*)&y_out[base + 4 * i] = o;
    }

    // ---- q projection for own bc (threads 0..99) ----
    if (t < 100) {
        float s = bd[t];
        const float* wr = Wd + t * 18;
        #pragma unroll
        for (int k = 0; k < 18; ++k) s = fmaf(scat[k], wr[k], s);
        q_out[(size_t)t * 1024 + bc] = s;
    }
}

extern "C" void kernel_launch(void* const* d_in, const int* in_sizes, int n_in,
                              void* d_out, int out_size, void* d_ws, size_t ws_size,
                              hipStream_t stream) {
    const float* query = (const float*)d_in[0];
    const float* value = (const float*)d_in[1];
    // d_in[2] hard_sigmoid_masks: unused by the reference
    const float* W1    = (const float*)d_in[3];
    const float* b1    = (const float*)d_in[4];
    const float* gamma = (const float*)d_in[5];
    const float* beta  = (const float*)d_in[6];
    const float* mean  = (const float*)d_in[7];
    const float* var   = (const float*)d_in[8];
    const float* W2    = (const float*)d_in[9];
    const float* b2    = (const float*)d_in[10];
    const float* Wl    = (const float*)d_in[11];
    const float* bl    = (const float*)d_in[12];
    const float* Wd    = (const float*)d_in[13];
    const float* bd    = (const float*)d_in[14];

    float* ws = (float*)d_ws;
    float* pooled = ws;            // 1024
    float* dp     = ws + 1024;     // 4096
    float* linbuf = ws + 5120;     // 18432

    float* q_out = (float*)d_out;            // 102400 floats
    float* y_out = (float*)d_out + 102400;   // 4194304 floats

    hipLaunchKernelGGL(pool_lin_kernel, dim3(1096), dim3(256), 0, stream,
                       value, query, Wl, bl, pooled, linbuf);
    hipLaunchKernelGGL(fc1_kernel,      dim3(1024), dim3(256), 0, stream,
                       pooled, W1, b1, gamma, beta, mean, var, dp);
    hipLaunchKernelGGL(stencil_kernel,  dim3(1024), dim3(256), 0, stream,
                       value, dp, W2, b2, linbuf, Wd, bd, q_out, y_out);
}